// Round 3
// baseline (199.583 us; speedup 1.0000x reference)
//
#include <hip/hip_runtime.h>

// Problem constants
#define NXC 128
#define NYC 128
#define NZC 4
#define BC  8
#define TC  10

// idx = (((b*T + t)*NZ + z)*NX + x)*NY + y
// y stride = 1, x stride = 128, z stride = 16384, t stride = 65536, b stride = 655360
#define TSTRIDE 65536           // NZ*NX*NY
#define NTOT    5242880         // B*T*NZ*NX*NY

__global__ __launch_bounds__(256) void blackoil_kernel(
    const float* __restrict__ pressure,
    const float* __restrict__ perm,
    const float* __restrict__ Q,
    const float* __restrict__ Qw,
    const float* __restrict__ Time_,
    const float* __restrict__ Phi,
    const float* __restrict__ Swini,
    const float* __restrict__ wsat,
    float* __restrict__ out)
{
    const int gid  = blockIdx.x * blockDim.x + threadIdx.x;
    const int base = gid << 2;                 // 4 contiguous y-elements per thread
    // NTOT / 4 / 256 = 5120 blocks exactly; no bounds check needed

    const int y = base & (NYC - 1);            // multiple of 4: 0..124
    const int x = (base >> 7) & (NXC - 1);
    const int t = (base >> 16) % TC;           // base>>16 == b*T + t (uniform per block)

    // x-neighbor row offsets with edge clamp
    const int xm = (x > 0)       ? -NYC : 0;
    const int xp = (x < NXC - 1) ?  NYC : 0;
    // y edge scalars (relative to base): element0's ym, element3's yp
    const int ymo = (y > 0)           ? -1 : 0;
    const int ypo = (y < NYC - 4)     ?  4 : 3;

    // ---- vector loads ----
    const float4 pc  = *(const float4*)(pressure + base);
    const float4 pxm = *(const float4*)(pressure + base + xm);
    const float4 pxp = *(const float4*)(pressure + base + xp);
    const float  pym = pressure[base + ymo];
    const float  pyp = pressure[base + ypo];

    const int i0 = base - t * TSTRIDE;         // same (b,z,x,y) at t = 0
    const float4 k0c = *(const float4*)(perm + i0);
    const float4 k0m = *(const float4*)(perm + i0 + xm);
    const float4 k0p = *(const float4*)(perm + i0 + xp);
    const float  kym = perm[i0 + ymo];
    const float  kyp = perm[i0 + ypo];

    const float4 kc  = *(const float4*)(perm + base);
    const float4 sat = *(const float4*)(wsat + base);

    const float sini = Swini[0];
    float4 pri;
    if (t == 0) { pri.x = pri.y = pri.z = pri.w = sini; }
    else        { pri = *(const float4*)(wsat + base - TSTRIDE); }

    const float4 qv  = *(const float4*)(Q     + base);
    const float4 qwv = *(const float4*)(Qw    + base);
    const float4 tv  = *(const float4*)(Time_ + base);
    const float4 phv = *(const float4*)(Phi   + base);

    // ---- mobility constants from siniuse ----
    const float S0 = (sini - 0.1f) * 1.25f;
    const float cw = S0 * S0;
    const float ct = cw + (1.0f - S0) * (1.0f - S0) * (1.0f / 2.75f);

    // ---- per-element arrays (registers) ----
    const float uc_ [4] = { pc.x,  pc.y,  pc.z,  pc.w  };
    const float uxm_[4] = { pxm.x, pxm.y, pxm.z, pxm.w };
    const float uxp_[4] = { pxp.x, pxp.y, pxp.z, pxp.w };
    const float uym_[4] = { pym,   pc.x,  pc.y,  pc.z  };
    const float uyp_[4] = { pc.y,  pc.z,  pc.w,  pyp   };

    const float k0m_[4] = { k0m.x, k0m.y, k0m.z, k0m.w };
    const float k0p_[4] = { k0p.x, k0p.y, k0p.z, k0p.w };
    const float kym_[4] = { kym,   k0c.x, k0c.y, k0c.z };
    const float kyp_[4] = { k0c.y, k0c.z, k0c.w, kyp   };

    const float kc_ [4] = { kc.x,  kc.y,  kc.z,  kc.w  };
    const float sa_ [4] = { sat.x, sat.y, sat.z, sat.w };
    const float pr_ [4] = { pri.x, pri.y, pri.z, pri.w };
    const float q_  [4] = { qv.x,  qv.y,  qv.z,  qv.w  };
    const float qw_ [4] = { qwv.x, qwv.y, qwv.z, qwv.w };
    const float tm_ [4] = { tv.x,  tv.y,  tv.z,  tv.w  };
    const float ph_ [4] = { phv.x, phv.y, phv.z, phv.w };

    float pl[4], sl[4];
    const float scale = 7.8125e-8f;            // dxf * 1e-5 = 1e-5/128

#pragma unroll
    for (int j = 0; j < 4; ++j) {
        // pressure derivatives (u = pressure * 1000)
        const float uc  = uc_[j]  * 1000.0f;
        const float uxm2= uxm_[j] * 1000.0f;
        const float uxp2= uxp_[j] * 1000.0f;
        const float uym2= uym_[j] * 1000.0f;
        const float uyp2= uyp_[j] * 1000.0f;

        const float dudx   = (uxp2 - uxm2) * 64.0f;
        const float dudy   = (uyp2 - uym2) * 64.0f;
        const float dduddx = (uxp2 - 2.0f * uc + uxm2) * 16384.0f;
        const float dduddy = (uyp2 - 2.0f * uc + uym2) * 16384.0f;

        // perm t=0 slice derivatives (a = 500*perm; offset cancels exactly)
        const float dpx = (k0p_[j] - k0m_[j]) * (500.0f * 64.0f);
        const float dpy = (kyp_[j] - kym_[j]) * (500.0f * 64.0f);
        const float dcdx = ct * dpx, dcdy = ct * dpy;
        const float dadx = cw * dpx, dady = cw * dpy;

        // time-varying mobility
        const float a     = 500.0f * kc_[j];
        const float dsw   = fmaxf(sa_[j] - pr_[j], 0.001f);
        const float S     = (pr_[j] - 0.1f) * 1.25f;
        const float Mw    = S * S;
        const float Mo    = (1.0f - S) * (1.0f - S) * (1.0f / 2.75f);
        const float a1    = (Mw + Mo) * a;
        const float a1w   = Mw * a;

        const float fin  = q_[j]  * 5000.0f;
        const float finw = qw_[j] * 5000.0f;
        const float dta  = tm_[j] * 6000.0f;

        pl[j] = scale * (fin + dcdx * dudx + a1 * dduddx
                             + dcdy * dudy + a1 * dduddy);
        const float flux = dadx * dudx + a1w * dduddx + dady * dudy + a1w * dduddy;
        sl[j] = scale * (ph_[j] * (dsw / dta) - (flux + finw));
    }

    float4 po = { pl[0], pl[1], pl[2], pl[3] };
    float4 so = { sl[0], sl[1], sl[2], sl[3] };
    *(float4*)(out + base)        = po;
    *(float4*)(out + base + NTOT) = so;
}

extern "C" void kernel_launch(void* const* d_in, const int* in_sizes, int n_in,
                              void* d_out, int out_size, void* d_ws, size_t ws_size,
                              hipStream_t stream) {
    const float* pressure = (const float*)d_in[0];
    const float* perm     = (const float*)d_in[1];
    const float* Q        = (const float*)d_in[2];
    const float* Qw       = (const float*)d_in[3];
    const float* Time_    = (const float*)d_in[4];
    // d_in[5] = Pini (unused by the reference)
    const float* Phi      = (const float*)d_in[6];
    const float* Swini    = (const float*)d_in[7];
    const float* wsat     = (const float*)d_in[8];
    float* out = (float*)d_out;

    const int threads = 256;
    const int blocks  = NTOT / 4 / threads;    // 5120
    blackoil_kernel<<<blocks, threads, 0, stream>>>(
        pressure, perm, Q, Qw, Time_, Phi, Swini, wsat, out);
}